// Round 9
// baseline (156.205 us; speedup 1.0000x reference)
//
#include <hip/hip_runtime.h>
#include <hip/hip_cooperative_groups.h>

namespace cg = cooperative_groups;

// B=4, N=384, D=64, K=2 hops
#define BB 4
#define NN 384
#define DD 64
#define XND (BB*NN*DD)   // 98304 floats per X time-slice; == 384 blocks * 256 threads

// ws layout (floats): [0, XND) = X2c packed [b][l][d] ; [XND, 2*XND) = U [b][j][d]

#define FMA4(c, a, x)                          \
    c.x = fmaf(a, x.x, c.x);                   \
    c.y = fmaf(a, x.y, c.y);                   \
    c.z = fmaf(a, x.z, c.z);                   \
    c.w = fmaf(a, x.w, c.w);

#define RED4(c)                                                         \
    c.x += __shfl_xor(c.x, 16); c.y += __shfl_xor(c.y, 16);             \
    c.z += __shfl_xor(c.z, 16); c.w += __shfl_xor(c.w, 16);             \
    c.x += __shfl_xor(c.x, 32); c.y += __shfl_xor(c.y, 32);             \
    c.z += __shfl_xor(c.z, 32); c.w += __shfl_xor(c.w, 32);

// One cooperative kernel, three phases separated by grid.sync():
//   P0: pack X2 -> ws[0:XND); stage W in LDS
//   P1: U[b,j,:] = X1[b,j,:] + sum_l A1[b,j,l] * X2c[b,l,:]
//   P2: out[b,i,:] = (X0[b,i,:] + sum_j A0[b,i,j] * U[b,j,:]) @ W
__global__ __launch_bounds__(256) void gnn_all(const float* __restrict__ A,
                                               const float* __restrict__ X,
                                               const float* __restrict__ W,
                                               float* __restrict__ ws,
                                               float* __restrict__ out) {
    __shared__ float part[4][4][DD];
    __shared__ float Ts[4][DD];
    __shared__ float Wsm[DD * DD];

    const int tid = threadIdx.x, lane = tid & 63, ks = tid >> 6;
    const int dg = lane & 15, jsub = lane >> 4;
    const int lbid = ((int)blockIdx.x & 7) * 48 + ((int)blockIdx.x >> 3); // XCD swizzle, 384%8==0
    const int b = lbid / 96, r0 = (lbid % 96) * 4;   // 4 output rows per block

    const float* X2c = ws;
    float* U = ws + XND;

    // ---------- phase 0: pack X2 slice; stage W ----------
    {
        const int gidx = (int)blockIdx.x * 256 + tid;   // grid covers XND exactly
        ws[gidx] = X[(size_t)gidx * 3 + 2];
        #pragma unroll
        for (int it = 0; it < 4; ++it) {
            int i4 = it * 256 + tid;
            *(float4*)&Wsm[i4 * 4] = ((const float4*)W)[i4];
        }
    }
    cg::this_grid().sync();

    // ---------- phase 1: U = X1 + A1 @ X2c ----------
    {
        const int lb = ks * 96 + jsub;
        const float* xp = X2c + ((size_t)b * NN + lb) * DD + dg * 4;
        const float* a0 = A + (((size_t)b * NN + r0 + 0) * NN + lb) * 2 + 1; // hop 1
        const float* a1 = A + (((size_t)b * NN + r0 + 1) * NN + lb) * 2 + 1;
        const float* a2 = A + (((size_t)b * NN + r0 + 2) * NN + lb) * 2 + 1;
        const float* a3 = A + (((size_t)b * NN + r0 + 3) * NN + lb) * 2 + 1;

        float4 c0{0,0,0,0}, c1{0,0,0,0}, c2{0,0,0,0}, c3{0,0,0,0};
        #pragma unroll 8
        for (int s = 0; s < 24; ++s) {              // l = lb + s*4
            float4 x = *(const float4*)(xp + s * 4 * DD);
            float v0 = a0[s * 8], v1 = a1[s * 8], v2 = a2[s * 8], v3 = a3[s * 8];
            FMA4(c0, v0, x) FMA4(c1, v1, x) FMA4(c2, v2, x) FMA4(c3, v3, x)
        }
        RED4(c0) RED4(c1) RED4(c2) RED4(c3)
        if (jsub == 0) {
            *(float4*)&part[ks][0][dg * 4] = c0;
            *(float4*)&part[ks][1][dg * 4] = c1;
            *(float4*)&part[ks][2][dg * 4] = c2;
            *(float4*)&part[ks][3][dg * 4] = c3;
        }
        __syncthreads();

        const int w = ks;                            // wave w -> row r0+w
        float t = X[(((size_t)b * NN + r0 + w) * DD + lane) * 3 + 1];
        t += part[0][w][lane] + part[1][w][lane] + part[2][w][lane] + part[3][w][lane];
        U[((size_t)b * NN + r0 + w) * DD + lane] = t;
    }
    cg::this_grid().sync();

    // ---------- phase 2: out = (X0 + A0 @ U) @ W ----------
    {
        const int lb = ks * 96 + jsub;
        const float* xp = U + ((size_t)b * NN + lb) * DD + dg * 4;
        const float* a0 = A + (((size_t)b * NN + r0 + 0) * NN + lb) * 2;   // hop 0
        const float* a1 = A + (((size_t)b * NN + r0 + 1) * NN + lb) * 2;
        const float* a2 = A + (((size_t)b * NN + r0 + 2) * NN + lb) * 2;
        const float* a3 = A + (((size_t)b * NN + r0 + 3) * NN + lb) * 2;

        float4 c0{0,0,0,0}, c1{0,0,0,0}, c2{0,0,0,0}, c3{0,0,0,0};
        #pragma unroll 8
        for (int s = 0; s < 24; ++s) {
            float4 x = *(const float4*)(xp + s * 4 * DD);
            float v0 = a0[s * 8], v1 = a1[s * 8], v2 = a2[s * 8], v3 = a3[s * 8];
            FMA4(c0, v0, x) FMA4(c1, v1, x) FMA4(c2, v2, x) FMA4(c3, v3, x)
        }
        RED4(c0) RED4(c1) RED4(c2) RED4(c3)
        if (jsub == 0) {
            *(float4*)&part[ks][0][dg * 4] = c0;
            *(float4*)&part[ks][1][dg * 4] = c1;
            *(float4*)&part[ks][2][dg * 4] = c2;
            *(float4*)&part[ks][3][dg * 4] = c3;
        }
        __syncthreads();

        const int w = ks;
        float t = X[(((size_t)b * NN + r0 + w) * DD + lane) * 3 + 0];
        t += part[0][w][lane] + part[1][w][lane] + part[2][w][lane] + part[3][w][lane];
        Ts[w][lane] = t;
        __syncthreads();

        float o = 0.f;
        #pragma unroll 16
        for (int d = 0; d < DD; ++d)
            o = fmaf(Ts[w][d], Wsm[d * DD + lane], o);   // broadcast * stride-1
        out[((size_t)b * NN + r0 + w) * DD + lane] = o;
    }
}

extern "C" void kernel_launch(void* const* d_in, const int* in_sizes, int n_in,
                              void* d_out, int out_size, void* d_ws, size_t ws_size,
                              hipStream_t stream) {
    const float* A = (const float*)d_in[0];
    const float* X = (const float*)d_in[1];
    const float* W = (const float*)d_in[2];
    float* out = (float*)d_out;
    float* ws  = (float*)d_ws;   // uses 2*XND*4 = 786432 bytes

    void* args[] = {(void*)&A, (void*)&X, (void*)&W, (void*)&ws, (void*)&out};
    hipLaunchCooperativeKernel((const void*)gnn_all,
                               dim3(BB * NN / 4), dim3(256),
                               args, 0, stream);
}

// Round 10
// 77.428 us; speedup vs baseline: 2.0174x; 2.0174x over previous
//
#include <hip/hip_runtime.h>

// B=4, N=384, D=64, K=2 hops
#define BB 4
#define NN 384
#define DD 64
#define XND (BB*NN*DD)   // 98304 floats

// ws layout (floats): [0, XND) = U [b][j][d]

#define FMA4(c, a, x)                          \
    c.x = fmaf(a, x.x, c.x);                   \
    c.y = fmaf(a, x.y, c.y);                   \
    c.z = fmaf(a, x.z, c.z);                   \
    c.w = fmaf(a, x.w, c.w);

#define RED4(c)                                                         \
    c.x += __shfl_xor(c.x, 16); c.y += __shfl_xor(c.y, 16);             \
    c.z += __shfl_xor(c.z, 16); c.w += __shfl_xor(c.w, 16);             \
    c.x += __shfl_xor(c.x, 32); c.y += __shfl_xor(c.y, 32);             \
    c.z += __shfl_xor(c.z, 32); c.w += __shfl_xor(c.w, 32);

// U[b,j,d] = X[b,j,d,1] + sum_l A[b,j,l,1] * X[b,l,d,2]
// block = 4 rows; wave ks = K-quarter (96 l's); lane = (jsub = l mod 4, dg = d quad)
// X2 read DIRECTLY from interleaved X (stride-3 scalars; 4 loads share 12 lines/l)
__global__ __launch_bounds__(256) void g2_u(const float* __restrict__ A,
                                            const float* __restrict__ X,
                                            float* __restrict__ ws) {
    __shared__ float part[4][4][DD];
    float* U = ws;

    const int tid = threadIdx.x, lane = tid & 63, ks = tid >> 6;
    const int dg = lane & 15, jsub = lane >> 4;
    const int lbid = ((int)blockIdx.x & 7) * 48 + ((int)blockIdx.x >> 3); // XCD swizzle, 384%8==0
    const int b = lbid / 96, j0 = (lbid % 96) * 4;

    const int lb = ks * 96 + jsub;
    // X2 element (b, l, d, t=2) at X[((b*NN+l)*DD + d)*3 + 2]; d = dg*4+q
    const float* xp = X + ((size_t)(b * NN + lb) * DD) * 3 + 2 + dg * 12;
    const float* a0 = A + (((size_t)b * NN + j0 + 0) * NN + lb) * 2 + 1;
    const float* a1 = A + (((size_t)b * NN + j0 + 1) * NN + lb) * 2 + 1;
    const float* a2 = A + (((size_t)b * NN + j0 + 2) * NN + lb) * 2 + 1;
    const float* a3 = A + (((size_t)b * NN + j0 + 3) * NN + lb) * 2 + 1;

    float4 c0{0,0,0,0}, c1{0,0,0,0}, c2{0,0,0,0}, c3{0,0,0,0};
    #pragma unroll 8
    for (int s = 0; s < 24; ++s) {              // l = lb + s*4 ; row stride = 4*DD*3 = 768
        float4 x;
        x.x = xp[s * 768 + 0];
        x.y = xp[s * 768 + 3];
        x.z = xp[s * 768 + 6];
        x.w = xp[s * 768 + 9];
        float v0 = a0[s * 8], v1 = a1[s * 8], v2 = a2[s * 8], v3 = a3[s * 8];
        FMA4(c0, v0, x) FMA4(c1, v1, x) FMA4(c2, v2, x) FMA4(c3, v3, x)
    }
    RED4(c0) RED4(c1) RED4(c2) RED4(c3)
    if (jsub == 0) {
        *(float4*)&part[ks][0][dg * 4] = c0;
        *(float4*)&part[ks][1][dg * 4] = c1;
        *(float4*)&part[ks][2][dg * 4] = c2;
        *(float4*)&part[ks][3][dg * 4] = c3;
    }
    __syncthreads();

    const int w = ks;                            // wave w -> row j0+w
    float t = X[(((size_t)b * NN + j0 + w) * DD + lane) * 3 + 1];
    t += part[0][w][lane] + part[1][w][lane] + part[2][w][lane] + part[3][w][lane];
    U[((size_t)b * NN + j0 + w) * DD + lane] = t;
}

// out[b,i,:] = (X[b,i,:,0] + sum_j A[b,i,j,0] * U[b,j,:]) @ W
__global__ __launch_bounds__(256) void g3_out(const float* __restrict__ A,
                                              const float* __restrict__ X,
                                              const float* __restrict__ W,
                                              const float* __restrict__ ws,
                                              float* __restrict__ out) {
    __shared__ float part[4][4][DD];
    __shared__ float Ts[4][DD];
    __shared__ float Wsm[DD * DD];
    const float* U = ws;

    const int tid = threadIdx.x, lane = tid & 63, ks = tid >> 6;
    const int dg = lane & 15, jsub = lane >> 4;
    const int lbid = ((int)blockIdx.x & 7) * 48 + ((int)blockIdx.x >> 3);
    const int b = lbid / 96, i0 = (lbid % 96) * 4;

    // stage W (coalesced float4), visible after first barrier
    #pragma unroll
    for (int it = 0; it < 4; ++it) {
        int i4 = it * 256 + tid;
        *(float4*)&Wsm[i4 * 4] = ((const float4*)W)[i4];
    }

    const int lb = ks * 96 + jsub;
    const float* xp = U + ((size_t)b * NN + lb) * DD + dg * 4;
    const float* a0 = A + (((size_t)b * NN + i0 + 0) * NN + lb) * 2;   // hop 0
    const float* a1 = A + (((size_t)b * NN + i0 + 1) * NN + lb) * 2;
    const float* a2 = A + (((size_t)b * NN + i0 + 2) * NN + lb) * 2;
    const float* a3 = A + (((size_t)b * NN + i0 + 3) * NN + lb) * 2;

    float4 c0{0,0,0,0}, c1{0,0,0,0}, c2{0,0,0,0}, c3{0,0,0,0};
    #pragma unroll 8
    for (int s = 0; s < 24; ++s) {
        float4 x = *(const float4*)(xp + s * 4 * DD);
        float v0 = a0[s * 8], v1 = a1[s * 8], v2 = a2[s * 8], v3 = a3[s * 8];
        FMA4(c0, v0, x) FMA4(c1, v1, x) FMA4(c2, v2, x) FMA4(c3, v3, x)
    }
    RED4(c0) RED4(c1) RED4(c2) RED4(c3)
    if (jsub == 0) {
        *(float4*)&part[ks][0][dg * 4] = c0;
        *(float4*)&part[ks][1][dg * 4] = c1;
        *(float4*)&part[ks][2][dg * 4] = c2;
        *(float4*)&part[ks][3][dg * 4] = c3;
    }
    __syncthreads();

    const int w = ks;
    float t = X[(((size_t)b * NN + i0 + w) * DD + lane) * 3 + 0];
    t += part[0][w][lane] + part[1][w][lane] + part[2][w][lane] + part[3][w][lane];
    Ts[w][lane] = t;
    __syncthreads();

    float o = 0.f;
    #pragma unroll 16
    for (int d = 0; d < DD; ++d)
        o = fmaf(Ts[w][d], Wsm[d * DD + lane], o);   // broadcast * stride-1
    out[((size_t)b * NN + i0 + w) * DD + lane] = o;
}

extern "C" void kernel_launch(void* const* d_in, const int* in_sizes, int n_in,
                              void* d_out, int out_size, void* d_ws, size_t ws_size,
                              hipStream_t stream) {
    const float* A = (const float*)d_in[0];
    const float* X = (const float*)d_in[1];
    const float* W = (const float*)d_in[2];
    float* out = (float*)d_out;
    float* ws  = (float*)d_ws;   // uses XND*4 = 393216 bytes

    g2_u  <<<dim3(BB * NN / 4), dim3(256), 0, stream>>>(A, X, ws);
    g3_out<<<dim3(BB * NN / 4), dim3(256), 0, stream>>>(A, X, W, ws, out);
}

// Round 15
// 70.532 us; speedup vs baseline: 2.2147x; 1.0978x over previous
//
#include <hip/hip_runtime.h>

// B=4, N=384, D=64, K=2 hops
#define BB 4
#define NN 384
#define DD 64
#define XND (BB*NN*DD)   // 98304 floats per X time-slice

// ws layout (floats): [0, XND) = X2c packed [b][l][d] ; [XND, 2*XND) = U [b][j][d]

__global__ __launch_bounds__(256) void g1_pack(const float* __restrict__ X,
                                               float* __restrict__ ws) {
    // one float4 of packed X2 per thread; 96 blocks cover XND/4 = 24576 quads
    const int q  = blockIdx.x * 256 + threadIdx.x;   // quad index
    const int row = q >> 4, h = q & 15;              // row = b*NN+l ; h = d quad
    const float* src = X + (size_t)row * DD * 3 + h * 12 + 2;
    float4 v;
    v.x = src[0]; v.y = src[3]; v.z = src[6]; v.w = src[9];
    *(float4*)&ws[(size_t)row * DD + h * 4] = v;
}

#define FMA4(c, a, x)                          \
    c.x = fmaf(a, x.x, c.x);                   \
    c.y = fmaf(a, x.y, c.y);                   \
    c.z = fmaf(a, x.z, c.z);                   \
    c.w = fmaf(a, x.w, c.w);

#define RED4(c)                                                         \
    c.x += __shfl_xor(c.x, 16); c.y += __shfl_xor(c.y, 16);             \
    c.z += __shfl_xor(c.z, 16); c.w += __shfl_xor(c.w, 16);             \
    c.x += __shfl_xor(c.x, 32); c.y += __shfl_xor(c.y, 32);             \
    c.z += __shfl_xor(c.z, 32); c.w += __shfl_xor(c.w, 32);

// U[b,j,d] = X[b,j,d,1] + sum_l A[b,j,l,1] * X2c[b,l,d]
// block = 2 rows; 768 blocks (3/CU); wave ks = K-quarter; lane = (jsub, dg)
__global__ __launch_bounds__(256) void g2_u(const float* __restrict__ A,
                                            const float* __restrict__ X,
                                            float* __restrict__ ws) {
    __shared__ float part[4][2][DD];
    const float* X2c = ws;
    float* U = ws + XND;

    const int tid = threadIdx.x, lane = tid & 63, ks = tid >> 6;
    const int dg = lane & 15, jsub = lane >> 4;
    const int lbid = ((int)blockIdx.x & 7) * 96 + ((int)blockIdx.x >> 3); // 768%8==0
    const int b = lbid / 192, j0 = (lbid % 192) * 2;

    const int lb = ks * 96 + jsub;
    const float* xp = X2c + ((size_t)b * NN + lb) * DD + dg * 4;
    const float* a0 = A + (((size_t)b * NN + j0 + 0) * NN + lb) * 2 + 1;  // hop 1
    const float* a1 = A + (((size_t)b * NN + j0 + 1) * NN + lb) * 2 + 1;

    float4 c0{0,0,0,0}, c1{0,0,0,0};
    #pragma unroll 8
    for (int s = 0; s < 24; ++s) {              // l = lb + s*4
        float4 x = *(const float4*)(xp + s * 4 * DD);
        float v0 = a0[s * 8], v1 = a1[s * 8];
        FMA4(c0, v0, x) FMA4(c1, v1, x)
    }
    RED4(c0) RED4(c1)
    if (jsub == 0) {
        *(float4*)&part[ks][0][dg * 4] = c0;
        *(float4*)&part[ks][1][dg * 4] = c1;
    }
    __syncthreads();

    const int w = ks;
    if (w < 2) {
        float t = X[(((size_t)b * NN + j0 + w) * DD + lane) * 3 + 1];
        t += part[0][w][lane] + part[1][w][lane] + part[2][w][lane] + part[3][w][lane];
        U[((size_t)b * NN + j0 + w) * DD + lane] = t;
    }
}

// out[b,i,:] = (X[b,i,:,0] + sum_j A[b,i,j,0] * U[b,j,:]) @ W
__global__ __launch_bounds__(256) void g3_out(const float* __restrict__ A,
                                              const float* __restrict__ X,
                                              const float* __restrict__ W,
                                              const float* __restrict__ ws,
                                              float* __restrict__ out) {
    __shared__ float part[4][2][DD];
    __shared__ float Ts[2][DD];
    __shared__ float Wsm[DD * DD];
    const float* U = ws + XND;

    const int tid = threadIdx.x, lane = tid & 63, ks = tid >> 6;
    const int dg = lane & 15, jsub = lane >> 4;
    const int lbid = ((int)blockIdx.x & 7) * 96 + ((int)blockIdx.x >> 3);
    const int b = lbid / 192, i0 = (lbid % 192) * 2;

    // stage W (coalesced float4), visible after first barrier
    #pragma unroll
    for (int it = 0; it < 4; ++it) {
        int i4 = it * 256 + tid;
        *(float4*)&Wsm[i4 * 4] = ((const float4*)W)[i4];
    }

    const int lb = ks * 96 + jsub;
    const float* xp = U + ((size_t)b * NN + lb) * DD + dg * 4;
    const float* a0 = A + (((size_t)b * NN + i0 + 0) * NN + lb) * 2;   // hop 0
    const float* a1 = A + (((size_t)b * NN + i0 + 1) * NN + lb) * 2;

    float4 c0{0,0,0,0}, c1{0,0,0,0};
    #pragma unroll 8
    for (int s = 0; s < 24; ++s) {
        float4 x = *(const float4*)(xp + s * 4 * DD);
        float v0 = a0[s * 8], v1 = a1[s * 8];
        FMA4(c0, v0, x) FMA4(c1, v1, x)
    }
    RED4(c0) RED4(c1)
    if (jsub == 0) {
        *(float4*)&part[ks][0][dg * 4] = c0;
        *(float4*)&part[ks][1][dg * 4] = c1;
    }
    __syncthreads();

    const int w = ks;
    if (w < 2) {
        float t = X[(((size_t)b * NN + i0 + w) * DD + lane) * 3 + 0];
        t += part[0][w][lane] + part[1][w][lane] + part[2][w][lane] + part[3][w][lane];
        Ts[w][lane] = t;
    }
    __syncthreads();

    if (w < 2) {
        float o = 0.f;
        #pragma unroll 16
        for (int d = 0; d < DD; ++d)
            o = fmaf(Ts[w][d], Wsm[d * DD + lane], o);   // broadcast * stride-1
        out[((size_t)b * NN + i0 + w) * DD + lane] = o;
    }
}

extern "C" void kernel_launch(void* const* d_in, const int* in_sizes, int n_in,
                              void* d_out, int out_size, void* d_ws, size_t ws_size,
                              hipStream_t stream) {
    const float* A = (const float*)d_in[0];
    const float* X = (const float*)d_in[1];
    const float* W = (const float*)d_in[2];
    float* out = (float*)d_out;
    float* ws  = (float*)d_ws;   // uses 2*XND*4 = 786432 bytes

    g1_pack<<<dim3(XND / 1024), dim3(256), 0, stream>>>(X, ws);   // 96 blocks
    g2_u  <<<dim3(BB * NN / 2), dim3(256), 0, stream>>>(A, X, ws);        // 768
    g3_out<<<dim3(BB * NN / 2), dim3(256), 0, stream>>>(A, X, W, ws, out); // 768
}